// Round 1
// baseline (17.814 us; speedup 1.0000x reference)
//
#include <hip/hip_runtime.h>

// Quantum patch encoder: 4-wire circuit, 16 real amplitudes per batch element.
// state idx = w0*8 + w1*4 + w2*2 + w3  (wire w -> bit position 3-w)

__global__ __launch_bounds__(256) void qpe_kernel(
    const float* __restrict__ inputs,   // (B, 4)
    const float* __restrict__ weights,  // (8,)
    float* __restrict__ out,            // (B, 4)
    int B)
{
    int b = blockIdx.x * blockDim.x + threadIdx.x;
    if (b >= B) return;

    // Uniform variational angles (same for all lanes; cheap with fast sincos)
    float cw[8], sw[8];
#pragma unroll
    for (int i = 0; i < 8; ++i) {
        float h = weights[i] * 0.5f;
        __sincosf(h, &sw[i], &cw[i]);
    }

    // Per-element encoding angles
    float4 x = *reinterpret_cast<const float4*>(inputs + (size_t)b * 4);
    float c[4], s[4];
    __sincosf(x.x * 0.5f, &s[0], &c[0]);
    __sincosf(x.y * 0.5f, &s[1], &c[1]);
    __sincosf(x.z * 0.5f, &s[2], &c[2]);
    __sincosf(x.w * 0.5f, &s[3], &c[3]);

    // Encoded state = product state: amp[idx] = prod_w (bit_w ? sin : cos)
    float amp[16];
#pragma unroll
    for (int idx = 0; idx < 16; ++idx) {
        float a = ((idx >> 3) & 1) ? s[0] : c[0];
        a *= ((idx >> 2) & 1) ? s[1] : c[1];
        a *= ((idx >> 1) & 1) ? s[2] : c[2];
        a *= ( idx       & 1) ? s[3] : c[3];
        amp[idx] = a;
    }

    // Variational layer: RY(weights[i]) on wire i%4, then CNOT(i%4, (i+1)%4)
#pragma unroll
    for (int i = 0; i < 8; ++i) {
        const int q  = i & 3;
        const int t  = (i + 1) & 3;
        const int qm = 1 << (3 - q);
        const int tm = 1 << (3 - t);
        const float ci = cw[i], si = sw[i];
        // RY on wire q
#pragma unroll
        for (int idx = 0; idx < 16; ++idx) {
            if (idx & qm) continue;
            float a0 = amp[idx], a1 = amp[idx | qm];
            amp[idx]      = ci * a0 - si * a1;
            amp[idx | qm] = si * a0 + ci * a1;
        }
        // CNOT(q -> t): swap target bit where control bit = 1 (register perm)
#pragma unroll
        for (int idx = 0; idx < 16; ++idx) {
            if (!(idx & qm) || (idx & tm)) continue;
            float tmp = amp[idx];
            amp[idx]      = amp[idx | tm];
            amp[idx | tm] = tmp;
        }
    }

    // Measurement: <Z_w> = sum_{bit(3-w)=0} amp^2 - sum_{bit(3-w)=1} amp^2
    float p[16];
#pragma unroll
    for (int idx = 0; idx < 16; ++idx) p[idx] = amp[idx] * amp[idx];

    float z[4];
#pragma unroll
    for (int w = 0; w < 4; ++w) {
        const int m = 1 << (3 - w);
        float acc = 0.0f;
#pragma unroll
        for (int idx = 0; idx < 16; ++idx)
            acc += (idx & m) ? -p[idx] : p[idx];
        z[w] = acc;
    }

    *reinterpret_cast<float4*>(out + (size_t)b * 4) = make_float4(z[0], z[1], z[2], z[3]);
}

extern "C" void kernel_launch(void* const* d_in, const int* in_sizes, int n_in,
                              void* d_out, int out_size, void* d_ws, size_t ws_size,
                              hipStream_t stream) {
    const float* inputs  = (const float*)d_in[0];   // (B, 4) f32
    const float* weights = (const float*)d_in[1];   // (8,)   f32
    float* out = (float*)d_out;                     // (B, 4) f32
    const int B = in_sizes[0] / 4;

    const int block = 256;
    const int grid  = (B + block - 1) / block;
    qpe_kernel<<<grid, block, 0, stream>>>(inputs, weights, out, B);
}

// Round 2
// 15.508 us; speedup vs baseline: 1.1487x; 1.1487x over previous
//
#include <hip/hip_runtime.h>

// Quantum patch encoder: 4-wire circuit, 16 real amplitudes per batch element.
// Packed-FP32 formulation: state as 8 x float2 (v2f). float2 index k encodes
// wires 0..2 (w0=bit2, w1=bit1, w2=bit0); components .x/.y = wire3 = 0/1.
// gfx950 has V_PK_FMA_F32 -> <2 x float> math runs at 2x scalar f32 rate.

typedef float v2f __attribute__((ext_vector_type(2)));

__global__ __launch_bounds__(256) void qpe_kernel(
    const float* __restrict__ inputs,   // (B, 4)
    const float* __restrict__ weights,  // (8,)
    float* __restrict__ out,            // (B, 4)
    int B)
{
    const int tid = blockIdx.x * blockDim.x + threadIdx.x;
    const int S   = gridDim.x * blockDim.x;   // elements handled per j-step

    // Uniform variational angles (scalar loads; amortized over 4 elements)
    float cw[8], sw[8];
#pragma unroll
    for (int i = 0; i < 8; ++i) {
        float h = weights[i] * 0.5f;
        sw[i] = __sinf(h);
        cw[i] = __cosf(h);
    }

#pragma unroll
    for (int j = 0; j < 4; ++j) {
        const int b = tid + j * S;
        if (b >= B) continue;

        float4 x = *reinterpret_cast<const float4*>(inputs + (size_t)b * 4);
        float c0 = __cosf(x.x * 0.5f), s0 = __sinf(x.x * 0.5f);
        float c1 = __cosf(x.y * 0.5f), s1 = __sinf(x.y * 0.5f);
        float c2 = __cosf(x.z * 0.5f), s2 = __sinf(x.z * 0.5f);
        float c3 = __cosf(x.w * 0.5f), s3 = __sinf(x.w * 0.5f);

        // Encoded product state
        const v2f e3 = {c3, s3};
        float f01[4];                     // f0[b0]*f1[b1]
        f01[0] = c0 * c1; f01[1] = c0 * s1; f01[2] = s0 * c1; f01[3] = s0 * s1;
        v2f amp[8];
#pragma unroll
        for (int k = 0; k < 8; ++k) {
            float p = f01[k >> 1] * ((k & 1) ? s2 : c2);
            amp[k] = p * e3;
        }

        // Variational layer: RY(w_i) on wire i%4, CNOT(i%4, (i+1)%4)
#pragma unroll
        for (int i = 0; i < 8; ++i) {
            const int q = i & 3;
            const float ci = cw[i], si = sw[i];
            if (q < 3) {
                const int m2 = 1 << (2 - q);   // wire q bit within k
#pragma unroll
                for (int k = 0; k < 8; ++k) {
                    if (k & m2) continue;
                    v2f a0 = amp[k], a1 = amp[k | m2];
                    amp[k]      = ci * a0 - si * a1;
                    amp[k | m2] = si * a0 + ci * a1;
                }
            } else {
                // RY on wire 3: intra-float2 rotation (op_sel swizzle is free)
                const v2f sv = {-si, si};
#pragma unroll
                for (int k = 0; k < 8; ++k) {
                    v2f a = amp[k];
                    v2f sp = {a.y, a.x};
                    amp[k] = ci * a + sv * sp;
                }
            }
            // CNOT(q -> t), t = (i+1)&3 : pure permutation
            if (q == 0) {            // CNOT(0,1): k bit2=1, swap bit1
                v2f t4 = amp[4]; amp[4] = amp[6]; amp[6] = t4;
                v2f t5 = amp[5]; amp[5] = amp[7]; amp[7] = t5;
            } else if (q == 1) {     // CNOT(1,2): k bit1=1, swap bit0
                v2f t2 = amp[2]; amp[2] = amp[3]; amp[3] = t2;
                v2f t6 = amp[6]; amp[6] = amp[7]; amp[7] = t6;
            } else if (q == 2) {     // CNOT(2,3): k bit0=1, swap components
#pragma unroll
                for (int k = 1; k < 8; k += 2) {
                    v2f a = amp[k];
                    amp[k] = (v2f){a.y, a.x};
                }
            } else {                 // CNOT(3,0): comp .y, swap k bit2
#pragma unroll
                for (int k = 0; k < 4; ++k) {
                    v2f lo = amp[k], hi = amp[k | 4];
                    amp[k]     = (v2f){lo.x, hi.y};
                    amp[k | 4] = (v2f){hi.x, lo.y};
                }
            }
        }

        // Probabilities
        v2f sq[8];
#pragma unroll
        for (int k = 0; k < 8; ++k) sq[k] = amp[k] * amp[k];

        // Partial-sum sharing for the 4 Walsh coefficients we need
        v2f a01 = sq[0] + sq[1], a23 = sq[2] + sq[3];
        v2f a45 = sq[4] + sq[5], a67 = sq[6] + sq[7];
        v2f b0123 = a01 + a23, b4567 = a45 + a67;
        v2f z0v = b0123 - b4567;                 // sign by k bit2 (wire0)
        v2f z1v = (a01 + a45) - (a23 + a67);     // sign by k bit1 (wire1)
        v2f ce = (sq[0] + sq[2]) + (sq[4] + sq[6]);
        v2f co = (sq[1] + sq[3]) + (sq[5] + sq[7]);
        v2f z2v = ce - co;                       // sign by k bit0 (wire2)
        v2f tot = b0123 + b4567;

        float4 z;
        z.x = z0v.x + z0v.y;
        z.y = z1v.x + z1v.y;
        z.z = z2v.x + z2v.y;
        z.w = tot.x - tot.y;                     // sign by wire3 component
        *reinterpret_cast<float4*>(out + (size_t)b * 4) = z;
    }
}

extern "C" void kernel_launch(void* const* d_in, const int* in_sizes, int n_in,
                              void* d_out, int out_size, void* d_ws, size_t ws_size,
                              hipStream_t stream) {
    const float* inputs  = (const float*)d_in[0];   // (B, 4) f32
    const float* weights = (const float*)d_in[1];   // (8,)   f32
    float* out = (float*)d_out;                     // (B, 4) f32
    const int B = in_sizes[0] / 4;

    const int block = 256;
    const int elems_per_thread = 4;
    const int threads = (B + elems_per_thread - 1) / elems_per_thread;
    const int grid = (threads + block - 1) / block;
    qpe_kernel<<<grid, block, 0, stream>>>(inputs, weights, out, B);
}